// Round 13
// baseline (397.503 us; speedup 1.0000x reference)
//
#include <hip/hip_runtime.h>
#include <math.h>
#include <stdint.h>

typedef __attribute__((ext_vector_type(8))) _Float16 f16x8;
typedef __attribute__((ext_vector_type(2))) __fp16 fp16x2;
typedef __attribute__((ext_vector_type(4))) float f32x4;
typedef __attribute__((ext_vector_type(16))) float f32x16;

static __device__ __forceinline__ unsigned short f2h(float f) {
  union { _Float16 h; unsigned short u; } v; v.h = (_Float16)f;
  return v.u;
}
static __device__ __forceinline__ float h2f(unsigned short u) {
  union { unsigned short u; _Float16 h; } v; v.u = u;
  return (float)v.h;
}
static __device__ __forceinline__ unsigned pkrtz(float a, float b) {
  union { fp16x2 h; unsigned u; } v;
  v.h = __builtin_amdgcn_cvt_pkrtz(a, b);
  return v.u;
}

#define GLOAD_LDS16(g, l) __builtin_amdgcn_global_load_lds( \
    (const __attribute__((address_space(1))) void*)(g),     \
    (__attribute__((address_space(3))) void*)(l), 16, 0, 0)

// ---------------- pack weights: W2 = [[Wr,-Wi],[Wi,Wr]] (1024x1024 f16), bias2 = br∓bi ----------------
__global__ __launch_bounds__(256) void pack_w(
    const float* __restrict__ Wr, const float* __restrict__ Wi,
    const float* __restrict__ br, const float* __restrict__ bi,
    unsigned short* __restrict__ W2, float* __restrict__ bias2) {
  int idx = blockIdx.x * 256 + threadIdx.x;
  int m = idx >> 10, k = idx & 1023;
  int o = m & 511, d = k & 511;
  float v;
  if (m < 512) v = (k < 512) ? Wr[o * 512 + d] : -Wi[o * 512 + d];
  else         v = (k < 512) ? Wi[o * 512 + d] :  Wr[o * 512 + d];
  W2[idx] = f2h(v);
  if (idx < 1024) {
    int oo = idx & 511;
    bias2[idx] = (idx < 512) ? (br[oo] - bi[oo]) : (br[oo] + bi[oo]);
  }
}

// ---------------- pack x: (B,D,2,S) f32 -> XT[(b*2048+s)][(c*512+d)] f16 (B^T layout) ----------------
__global__ __launch_bounds__(256) void pack_x(
    const float* __restrict__ x, unsigned short* __restrict__ XT) {
  __shared__ unsigned short tl[64][72];
  const int t = threadIdx.x;
  const int sBase = blockIdx.x * 64, dBase = blockIdx.y * 64;
  const int b = blockIdx.z >> 1, c = blockIdx.z & 1;
  const int r = t >> 2, cb = (t & 3) * 16;
  const float* src = x + (((size_t)(b * 512 + dBase + r) * 2 + c) * 2048 + sBase + cb);
#pragma unroll
  for (int j = 0; j < 16; j += 4) {
    float4 v = *(const float4*)(src + j);
    tl[cb + j + 0][r] = f2h(v.x);
    tl[cb + j + 1][r] = f2h(v.y);
    tl[cb + j + 2][r] = f2h(v.z);
    tl[cb + j + 3][r] = f2h(v.w);
  }
  __syncthreads();
  const int s = t >> 2, dc = (t & 3) * 16;
  unsigned short* dst = XT + ((size_t)(b * 2048 + sBase + s)) * 1024 + c * 512 + dBase + dc;
  *(uint4*)dst = *(const uint4*)&tl[s][dc];
  *(uint4*)(dst + 8) = *(const uint4*)&tl[s][dc + 8];
}

// ---------------- GEMM: C[1024][8192] = A(1024x1024) * Bt(8192x1024)^T, f16 in, fp32 acc ----------------
// 1D grid, XCD-swizzled: xcd=bid&7 owns n-tiles [8*xcd, 8*xcd+8) -> A+B panels fit 4MB L2.
template <int MODE>
__global__ __launch_bounds__(256) void gemm_bt(
    const unsigned short* __restrict__ A, const unsigned short* __restrict__ Bt,
    const float* __restrict__ bias, unsigned short* __restrict__ Cb,
    float* __restrict__ Cf) {
  __shared__ unsigned short As[128 * 32];
  __shared__ unsigned short Bs[128 * 32];
  const int t = threadIdx.x;
  const int wave = t >> 6, lane = t & 63;
  const int wr = wave >> 1, wc = wave & 1;
  const int bid = blockIdx.x;
  const int xcd = bid & 7, g = bid >> 3;
  const int i = g & 63, z = g >> 6;
  const int nb = xcd * 8 + (i >> 3), mb = i & 7;
  const int mBase = mb * 128, nBase = nb * 128;
  A += (size_t)z * 1024 * 1024;
  bias += z * 1024;
  if (MODE == 0) Cb += (size_t)z * 1024 * 8192;
  const int lr = lane & 15, lk = (lane >> 4) * 8;
  f32x4 acc[4][4] = {};
  const int grow = wave * 32 + (lane >> 2);
  const int gcol = (lane & 3) * 8;
  const unsigned short* ga = A + (size_t)(mBase + grow) * 1024 + gcol;
  const unsigned short* gb = Bt + (size_t)(nBase + grow) * 1024 + gcol;
  unsigned short* lA = &As[wave * 1024];
  unsigned short* lB = &Bs[wave * 1024];
  for (int k0 = 0; k0 < 1024; k0 += 32) {
    __syncthreads();
    GLOAD_LDS16(ga + k0, lA);
    GLOAD_LDS16(ga + 16 * 1024 + k0, lA + 512);
    GLOAD_LDS16(gb + k0, lB);
    GLOAD_LDS16(gb + 16 * 1024 + k0, lB + 512);
    __syncthreads();
    f16x8 af[4], bfr[4];
#pragma unroll
    for (int i2 = 0; i2 < 4; ++i2) {
      af[i2]  = *(const f16x8*)&As[(wr * 64 + i2 * 16 + lr) * 32 + lk];
      bfr[i2] = *(const f16x8*)&Bs[(wc * 64 + i2 * 16 + lr) * 32 + lk];
    }
#pragma unroll
    for (int i2 = 0; i2 < 4; ++i2)
#pragma unroll
      for (int j = 0; j < 4; ++j)
        acc[i2][j] = __builtin_amdgcn_mfma_f32_16x16x32_f16(af[i2], bfr[j], acc[i2][j], 0, 0, 0);
  }
  const int cr = (lane >> 4) * 4, cc = lane & 15;
#pragma unroll
  for (int i2 = 0; i2 < 4; ++i2) {
#pragma unroll
    for (int j = 0; j < 4; ++j) {
      const int m0 = mBase + wr * 64 + i2 * 16 + cr;
      const int n0 = nBase + wc * 64 + j * 16 + cc;
#pragma unroll
      for (int g2 = 0; g2 < 4; ++g2) {
        float v = acc[i2][j][g2] + bias[m0 + g2];
        if (MODE == 0) {
          const int m = m0 + g2;
          if (z == 2) {
            // V fragment-major: [bh][tile32][ks4][j2][ri2][lane64][8]
            const int ri = m >> 9, mm = m & 511;
            const int h = mm >> 6, dloc = mm & 63;
            const int jj = dloc >> 5, q31 = dloc & 31;
            const int b = n0 >> 11, s = n0 & 2047;
            const int tile = s >> 6, ks = (s >> 4) & 3, hi = (s >> 3) & 1, e = s & 7;
            const size_t flat =
                ((((((size_t)(b * 8 + h) * 32 + tile) * 4 + ks) * 2 + jj) * 2 + ri) * 64 +
                 hi * 32 + q31) * 8 + e;
            Cb[flat] = f2h(v);
          } else {
            Cb[(size_t)m * 8192 + n0] = f2h(v);
          }
        } else {
          const int m = m0 + g2;
          const int c = m >> 9, o = m & 511;
          const int b = n0 >> 11, s = n0 & 2047;
          Cf[(size_t)b * 2097152 + (size_t)o * 4096 + c * 2048 + s] = v;
        }
      }
    }
  }
}

// ---------------- magnitudes: Qm row-major [(bh*2048+s)][64]; Km FRAGMENT-major ----------------
__global__ __launch_bounds__(256) void mag_qk(
    const unsigned short* __restrict__ Cq, const unsigned short* __restrict__ Ck,
    unsigned short* __restrict__ Qm, unsigned short* __restrict__ Km) {
  __shared__ unsigned short tl[64][72];
  const int isK = blockIdx.z;
  const unsigned short* C = isK ? Ck : Cq;
  unsigned short* Out = isK ? Km : Qm;
  const int t = threadIdx.x;
  const int sBase = blockIdx.x * 64;
  const int bh = blockIdx.y, b = bh >> 3, h = bh & 7;
  const int d = t >> 2, sc = (t & 3) * 16;
  const unsigned short* pr = C + (size_t)(h * 64 + d) * 8192 + b * 2048 + sBase + sc;
  const unsigned short* pi = pr + (size_t)512 * 8192;
  unsigned short rb[16], ib[16];
  *(uint4*)&rb[0] = *(const uint4*)pr;  *(uint4*)&rb[8] = *(const uint4*)(pr + 8);
  *(uint4*)&ib[0] = *(const uint4*)pi;  *(uint4*)&ib[8] = *(const uint4*)(pi + 8);
#pragma unroll
  for (int j = 0; j < 16; ++j) {
    float fr = h2f(rb[j]), fi = h2f(ib[j]);
    tl[sc + j][d] = f2h(sqrtf(fr * fr + fi * fi + 1e-8f));
  }
  __syncthreads();
  const int s = t >> 2, dc = (t & 3) * 16;
  if (isK) {
    const int kb = s >> 5, q31 = s & 31, db = dc >> 4;
    unsigned short* dstf = Out +
        ((((size_t)bh * 32 + blockIdx.x) * 2 + kb) * 4 + db) * 512 + (size_t)q31 * 8;
    *(uint4*)dstf = *(const uint4*)&tl[s][dc];               // hi = 0
    *(uint4*)(dstf + 256) = *(const uint4*)&tl[s][dc + 8];   // hi = 1
  } else {
    unsigned short* dst = Out + ((size_t)bh * 2048 + sBase + s) * 64 + dc;
    *(uint4*)dst = *(const uint4*)&tl[s][dc];
    *(uint4*)(dst + 8) = *(const uint4*)&tl[s][dc + 8];
  }
}

// ---------------- flash attention, KV-split x2; hard 128-VGPR cap + V reg time-share ----------------
// 1024 blocks; __launch_bounds__(256,4) -> 4 blocks/CU -> 4 waves/SIMD resident.
__global__ __launch_bounds__(256, 4) void attn(
    const unsigned short* __restrict__ Qm, const unsigned short* __restrict__ Km,
    const unsigned short* __restrict__ Vf, unsigned short* __restrict__ Op0,
    unsigned short* __restrict__ Op1, float2* __restrict__ ml) {
  const int t = threadIdx.x, wave = t >> 6, lane = t & 63;
  const int id = blockIdx.x;
  const int xcd = id & 7, within = id >> 3;
  const int bh = xcd * 4 + (within >> 5);
  const int rem = within & 31;
  const int qtile = rem >> 1, half = rem & 1;
  const int b = bh >> 3, h = bh & 7;
  const int q31 = lane & 31, hi = lane >> 5;
  const int qBase = qtile * 128 + wave * 32;
  const float ls = 0.18033688f;  // log2(e)/sqrt(DK)

  f16x8 qf[4];
  {
    const unsigned short* qp = Qm + ((size_t)bh * 2048 + qBase + q31) * 64 + hi * 8;
    qf[0] = *(const f16x8*)qp;
    qf[1] = *(const f16x8*)(qp + 16);
    qf[2] = *(const f16x8*)(qp + 32);
    qf[3] = *(const f16x8*)(qp + 48);
  }
  f32x16 Or[2] = {}, Oi[2] = {};
  float m = -1e30f, l = 0.f;

  const int tile0 = half * 16;
  const unsigned short* kptr = Km + (size_t)bh * 131072 + (size_t)tile0 * 4096 + (size_t)lane * 8;
  const unsigned short* vptr = Vf + (size_t)bh * 262144 + (size_t)tile0 * 8192 + (size_t)lane * 8;

  for (int it = 0; it < 16; ++it) {
    // ---- batch K loads (8 x 1KB coalesced) ----
    f16x8 kf[2][4];
#pragma unroll
    for (int kb = 0; kb < 2; ++kb)
#pragma unroll
      for (int db = 0; db < 4; ++db)
        kf[kb][db] = *(const f16x8*)(kptr + (size_t)(kb * 4 + db) * 512);
    __builtin_amdgcn_sched_barrier(0);
    // ---- QK^T (swapped): S[kb] = K x Q, col=q row=kv ----
    f32x16 S[2] = {};
#pragma unroll
    for (int kb = 0; kb < 2; ++kb)
#pragma unroll
      for (int db = 0; db < 4; ++db)
        S[kb] = __builtin_amdgcn_mfma_f32_32x32x16_f16(kf[kb][db], qf[db], S[kb], 0, 0, 0);
    // ---- batch Vr loads (8) into time-shared v[]; latency hides under softmax ----
    f16x8 v[4][2];
#pragma unroll
    for (int ks = 0; ks < 4; ++ks)
#pragma unroll
      for (int j = 0; j < 2; ++j)
        v[ks][j] = *(const f16x8*)(vptr + (size_t)((ks * 2 + j) * 2) * 512);
    __builtin_amdgcn_sched_barrier(0);
    // ---- row max (lane-local + 1 cross-half shuffle) ----
    float m0a = fmaxf(S[0][0], S[0][1]), m0b = fmaxf(S[0][2], S[0][3]);
#pragma unroll
    for (int r = 4; r < 16; r += 4) {
      m0a = fmaxf(m0a, fmaxf(S[0][r], S[0][r + 1]));
      m0b = fmaxf(m0b, fmaxf(S[0][r + 2], S[0][r + 3]));
    }
#pragma unroll
    for (int r = 0; r < 16; r += 4) {
      m0a = fmaxf(m0a, fmaxf(S[1][r], S[1][r + 1]));
      m0b = fmaxf(m0b, fmaxf(S[1][r + 2], S[1][r + 3]));
    }
    float vmax = fmaxf(m0a, m0b);
    vmax = fmaxf(vmax, __shfl_xor(vmax, 32, 64));
    float pmax = vmax * ls;
    // ---- defer-max rescale (rare): al lives at lane=q, O rows are q=qloc -> shfl ----
    if (__any(pmax > m + 8.0f)) {
      float mnew = fmaxf(m, pmax);
      float al = __builtin_amdgcn_exp2f(m - mnew);
      m = mnew;
      l *= al;
#pragma unroll
      for (int r = 0; r < 16; ++r) {
        const int qloc = (r & 3) + 8 * (r >> 2) + 4 * hi;
        float ao = __shfl(al, qloc, 64);
        Or[0][r] *= ao; Or[1][r] *= ao;
        Oi[0][r] *= ao; Oi[1][r] *= ao;
      }
    }
    // ---- P in place: S = exp2(S*ls - m); lane-local sum ----
    float ps0 = 0.f, ps1 = 0.f;
#pragma unroll
    for (int kb = 0; kb < 2; ++kb)
#pragma unroll
      for (int r = 0; r < 16; r += 2) {
        float pa_ = __builtin_amdgcn_exp2f(fmaf(S[kb][r], ls, -m));
        float pb_ = __builtin_amdgcn_exp2f(fmaf(S[kb][r + 1], ls, -m));
        S[kb][r] = pa_; S[kb][r + 1] = pb_;
        ps0 += pa_; ps1 += pb_;
      }
    float ps = ps0 + ps1;
    ps += __shfl_xor(ps, 32, 64);
    l += ps;
    // ---- P (=S) -> PV A-frags: cvt_pkrtz + permlane32_swap ----
    f16x8 pa[4];
#pragma unroll
    for (int ks = 0; ks < 4; ++ks) {
      const int kb = ks >> 1, off = 8 * (ks & 1);
      unsigned c0 = pkrtz(S[kb][off + 0], S[kb][off + 1]);
      unsigned c1 = pkrtz(S[kb][off + 2], S[kb][off + 3]);
      unsigned d0 = pkrtz(S[kb][off + 4], S[kb][off + 5]);
      unsigned d1 = pkrtz(S[kb][off + 6], S[kb][off + 7]);
      asm volatile("v_permlane32_swap_b32 %0, %1" : "+v"(c0), "+v"(d0));
      asm volatile("v_permlane32_swap_b32 %0, %1" : "+v"(c1), "+v"(d1));
      union { unsigned u[4]; f16x8 v; } w;
      w.u[0] = c0; w.u[1] = c1; w.u[2] = d0; w.u[3] = d1;
      pa[ks] = w.v;
    }
    // ---- PV real: consumes v (=Vr) ----
#pragma unroll
    for (int ks = 0; ks < 4; ++ks)
#pragma unroll
      for (int j = 0; j < 2; ++j)
        Or[j] = __builtin_amdgcn_mfma_f32_32x32x16_f16(pa[ks], v[ks][j], Or[j], 0, 0, 0);
    // ---- reload v with Vi (time-share); latency hides under Or MFMAs / other waves ----
#pragma unroll
    for (int ks = 0; ks < 4; ++ks)
#pragma unroll
      for (int j = 0; j < 2; ++j)
        v[ks][j] = *(const f16x8*)(vptr + (size_t)((ks * 2 + j) * 2) * 512 + 512);
    __builtin_amdgcn_sched_barrier(0);
    kptr += 4096; vptr += 8192;
    // ---- PV imag: consumes v (=Vi) ----
#pragma unroll
    for (int ks = 0; ks < 4; ++ks)
#pragma unroll
      for (int j = 0; j < 2; ++j)
        Oi[j] = __builtin_amdgcn_mfma_f32_32x32x16_f16(pa[ks], v[ks][j], Oi[j], 0, 0, 0);
  }
  // ---- epilogue: normalize by this half's l, store partial; record (m,l) ----
  unsigned short* Op = half ? Op1 : Op0;
  float linv = 1.0f / l;
#pragma unroll
  for (int r = 0; r < 16; ++r) {
    const int qloc = (r & 3) + 8 * (r >> 2) + 4 * hi;
    float iv = __shfl(linv, qloc, 64);
    unsigned short* orow = Op + ((size_t)b * 2048 + qBase + qloc) * 1024 + h * 64;
    orow[q31]       = f2h(Or[0][r] * iv);
    orow[32 + q31]  = f2h(Or[1][r] * iv);
    orow[512 + q31] = f2h(Oi[0][r] * iv);
    orow[544 + q31] = f2h(Oi[1][r] * iv);
  }
  if (hi == 0) {
    float2 v2; v2.x = m; v2.y = l;
    ml[(size_t)half * 65536 + (size_t)bh * 2048 + qBase + q31] = v2;
  }
}

// ---------------- combine: OutT = (w0*O0 + w1*O1)/(w0+w1), w_h = l_h*2^(m_h-M) ----------------
__global__ __launch_bounds__(256) void combine(
    const unsigned short* __restrict__ O0, const unsigned short* __restrict__ O1,
    const float2* __restrict__ ml, unsigned short* __restrict__ OutT) {
  const int tid = blockIdx.x * 256 + threadIdx.x;  // 524288 total
  const int d4 = tid & 3, h = (tid >> 2) & 7, c = (tid >> 5) & 1;
  const int q = (tid >> 6) & 2047, b = tid >> 17;
  const size_t bhq = (size_t)(b * 8 + h) * 2048 + q;
  float2 ml0 = ml[bhq];
  float2 ml1 = ml[65536 + bhq];
  float M = fmaxf(ml0.x, ml1.x);
  float w0 = ml0.y * exp2f(ml0.x - M);
  float w1 = ml1.y * exp2f(ml1.x - M);
  float inv = 1.0f / (w0 + w1);
  float s0 = w0 * inv, s1 = w1 * inv;
  const size_t off = ((size_t)b * 2048 + q) * 1024 + c * 512 + h * 64 + d4 * 16;
  const unsigned short* p0 = O0 + off;
  const unsigned short* p1 = O1 + off;
  unsigned short* po = OutT + off;
#pragma unroll
  for (int g = 0; g < 2; ++g) {
    uint4 a = *(const uint4*)(p0 + g * 8);
    uint4 bb = *(const uint4*)(p1 + g * 8);
    const unsigned short* ap = (const unsigned short*)&a;
    const unsigned short* bp = (const unsigned short*)&bb;
    unsigned short r[8];
#pragma unroll
    for (int e = 0; e < 8; ++e)
      r[e] = f2h(s0 * h2f(ap[e]) + s1 * h2f(bp[e]));
    *(uint4*)(po + g * 8) = *(const uint4*)r;
  }
}

extern "C" void kernel_launch(void* const* d_in, const int* in_sizes, int n_in,
                              void* d_out, int out_size, void* d_ws, size_t ws_size,
                              hipStream_t stream) {
  (void)in_sizes; (void)n_in; (void)out_size; (void)ws_size;
  const float* x = (const float*)d_in[0];

  // workspace layout: XT 16.78M | W2 8.39M | bias2 16K | Cqkv 50.33M  => ~75.5 MB
  unsigned short* XT = (unsigned short*)d_ws;
  unsigned short* W2 = XT + (size_t)8192 * 1024;
  float* bias2 = (float*)(W2 + (size_t)4 * 1024 * 1024);
  unsigned short* Cqkv = (unsigned short*)(bias2 + 4096);
  // Qm/Km live in d_out (dead before final GEMM overwrites d_out)
  unsigned short* Qm = (unsigned short*)d_out;
  unsigned short* Km = Qm + (size_t)4 * 8 * 2048 * 64;     // fragment-major
  // Partials/scratch in dead slabs:
  unsigned short* Op0 = XT;                                 // XT dead after gemm0
  unsigned short* Op1 = Km + (size_t)4 * 8 * 2048 * 64;     // d_out tail (16.78MB free)
  float2* ml = (float2*)(Cqkv + (size_t)1024 * 8192);       // Ck slab, dead after mag_qk
  unsigned short* Vf = Cqkv + (size_t)2 * 1024 * 8192;
  unsigned short* OutT = Cqkv;                              // Cq slab, dead after mag_qk

  for (int s = 0; s < 4; ++s) {
    pack_w<<<4096, 256, 0, stream>>>(
        (const float*)d_in[1 + 4 * s], (const float*)d_in[2 + 4 * s],
        (const float*)d_in[3 + 4 * s], (const float*)d_in[4 + 4 * s],
        W2 + (size_t)s * 1024 * 1024, bias2 + s * 1024);
  }
  pack_x<<<dim3(32, 8, 8), 256, 0, stream>>>(x, XT);
  gemm_bt<0><<<1536, 256, 0, stream>>>(W2, XT, bias2, Cqkv, nullptr);
  mag_qk<<<dim3(32, 32, 2), 256, 0, stream>>>(Cqkv, Cqkv + (size_t)1024 * 8192, Qm, Km);
  attn<<<1024, 256, 0, stream>>>(Qm, Km, Vf, Op0, Op1, ml);
  combine<<<2048, 256, 0, stream>>>(Op0, Op1, ml, OutT);
  gemm_bt<1><<<512, 256, 0, stream>>>(
      W2 + (size_t)3 * 1024 * 1024, OutT, bias2 + 3 * 1024, nullptr, (float*)d_out);
}

// Round 14
// 206.400 us; speedup vs baseline: 1.9259x; 1.9259x over previous
//
#include <hip/hip_runtime.h>
#include <math.h>
#include <stdint.h>

typedef __attribute__((ext_vector_type(8))) _Float16 f16x8;
typedef __attribute__((ext_vector_type(2))) __fp16 fp16x2;
typedef __attribute__((ext_vector_type(4))) float f32x4;
typedef __attribute__((ext_vector_type(16))) float f32x16;

static __device__ __forceinline__ unsigned short f2h(float f) {
  union { _Float16 h; unsigned short u; } v; v.h = (_Float16)f;
  return v.u;
}
static __device__ __forceinline__ float h2f(unsigned short u) {
  union { unsigned short u; _Float16 h; } v; v.u = u;
  return (float)v.h;
}
static __device__ __forceinline__ unsigned pkrtz(float a, float b) {
  union { fp16x2 h; unsigned u; } v;
  v.h = __builtin_amdgcn_cvt_pkrtz(a, b);
  return v.u;
}

#define GLOAD_LDS16(g, l) __builtin_amdgcn_global_load_lds( \
    (const __attribute__((address_space(1))) void*)(g),     \
    (__attribute__((address_space(3))) void*)(l), 16, 0, 0)

// ---------------- pack weights (all 4 sets in one dispatch): W2 = [[Wr,-Wi],[Wi,Wr]] ----------------
__global__ __launch_bounds__(256) void pack_w4(
    const float* __restrict__ Wr0, const float* __restrict__ Wi0,
    const float* __restrict__ br0, const float* __restrict__ bi0,
    const float* __restrict__ Wr1, const float* __restrict__ Wi1,
    const float* __restrict__ br1, const float* __restrict__ bi1,
    const float* __restrict__ Wr2, const float* __restrict__ Wi2,
    const float* __restrict__ br2, const float* __restrict__ bi2,
    const float* __restrict__ Wr3, const float* __restrict__ Wi3,
    const float* __restrict__ br3, const float* __restrict__ bi3,
    unsigned short* __restrict__ W2, float* __restrict__ bias2) {
  const int s = blockIdx.y;
  const float* Wr = (s == 0) ? Wr0 : (s == 1) ? Wr1 : (s == 2) ? Wr2 : Wr3;
  const float* Wi = (s == 0) ? Wi0 : (s == 1) ? Wi1 : (s == 2) ? Wi2 : Wi3;
  const float* br = (s == 0) ? br0 : (s == 1) ? br1 : (s == 2) ? br2 : br3;
  const float* bi = (s == 0) ? bi0 : (s == 1) ? bi1 : (s == 2) ? bi2 : bi3;
  W2 += (size_t)s * 1024 * 1024;
  bias2 += s * 1024;
  int idx = blockIdx.x * 256 + threadIdx.x;
  int m = idx >> 10, k = idx & 1023;
  int o = m & 511, d = k & 511;
  float v;
  if (m < 512) v = (k < 512) ? Wr[o * 512 + d] : -Wi[o * 512 + d];
  else         v = (k < 512) ? Wi[o * 512 + d] :  Wr[o * 512 + d];
  W2[idx] = f2h(v);
  if (idx < 1024) {
    int oo = idx & 511;
    bias2[idx] = (idx < 512) ? (br[oo] - bi[oo]) : (br[oo] + bi[oo]);
  }
}

// ---------------- pack x: (B,D,2,S) f32 -> XT[(b*2048+s)][(c*512+d)] f16 (B^T layout) ----------------
__global__ __launch_bounds__(256) void pack_x(
    const float* __restrict__ x, unsigned short* __restrict__ XT) {
  __shared__ unsigned short tl[64][72];
  const int t = threadIdx.x;
  const int sBase = blockIdx.x * 64, dBase = blockIdx.y * 64;
  const int b = blockIdx.z >> 1, c = blockIdx.z & 1;
  const int r = t >> 2, cb = (t & 3) * 16;
  const float* src = x + (((size_t)(b * 512 + dBase + r) * 2 + c) * 2048 + sBase + cb);
#pragma unroll
  for (int j = 0; j < 16; j += 4) {
    float4 v = *(const float4*)(src + j);
    tl[cb + j + 0][r] = f2h(v.x);
    tl[cb + j + 1][r] = f2h(v.y);
    tl[cb + j + 2][r] = f2h(v.z);
    tl[cb + j + 3][r] = f2h(v.w);
  }
  __syncthreads();
  const int s = t >> 2, dc = (t & 3) * 16;
  unsigned short* dst = XT + ((size_t)(b * 2048 + sBase + s)) * 1024 + c * 512 + dBase + dc;
  *(uint4*)dst = *(const uint4*)&tl[s][dc];
  *(uint4*)(dst + 8) = *(const uint4*)&tl[s][dc + 8];
}

// ---------------- GEMM: C[1024][8192] = A(1024x1024) * Bt(8192x1024)^T, f16 in, fp32 acc ----------------
// 1D grid, XCD-swizzled: xcd=bid&7 owns n-tiles [8*xcd, 8*xcd+8) -> A+B panels fit 4MB L2.
// MODE 0: z=0,1 (Q,K): f16 channel-major; z=2 (V): fragment-major V_f for attn.
// MODE 1: fp32 scattered into d_out (B,D,2,S).
template <int MODE>
__global__ __launch_bounds__(256) void gemm_bt(
    const unsigned short* __restrict__ A, const unsigned short* __restrict__ Bt,
    const float* __restrict__ bias, unsigned short* __restrict__ Cb,
    float* __restrict__ Cf) {
  __shared__ unsigned short As[128 * 32];
  __shared__ unsigned short Bs[128 * 32];
  const int t = threadIdx.x;
  const int wave = t >> 6, lane = t & 63;
  const int wr = wave >> 1, wc = wave & 1;
  const int bid = blockIdx.x;
  const int xcd = bid & 7, g = bid >> 3;
  const int i = g & 63, z = g >> 6;
  const int nb = xcd * 8 + (i >> 3), mb = i & 7;
  const int mBase = mb * 128, nBase = nb * 128;
  A += (size_t)z * 1024 * 1024;
  bias += z * 1024;
  if (MODE == 0) Cb += (size_t)z * 1024 * 8192;
  const int lr = lane & 15, lk = (lane >> 4) * 8;
  f32x4 acc[4][4] = {};
  const int grow = wave * 32 + (lane >> 2);
  const int gcol = (lane & 3) * 8;
  const unsigned short* ga = A + (size_t)(mBase + grow) * 1024 + gcol;
  const unsigned short* gb = Bt + (size_t)(nBase + grow) * 1024 + gcol;
  unsigned short* lA = &As[wave * 1024];
  unsigned short* lB = &Bs[wave * 1024];
  for (int k0 = 0; k0 < 1024; k0 += 32) {
    __syncthreads();
    GLOAD_LDS16(ga + k0, lA);
    GLOAD_LDS16(ga + 16 * 1024 + k0, lA + 512);
    GLOAD_LDS16(gb + k0, lB);
    GLOAD_LDS16(gb + 16 * 1024 + k0, lB + 512);
    __syncthreads();
    f16x8 af[4], bfr[4];
#pragma unroll
    for (int i2 = 0; i2 < 4; ++i2) {
      af[i2]  = *(const f16x8*)&As[(wr * 64 + i2 * 16 + lr) * 32 + lk];
      bfr[i2] = *(const f16x8*)&Bs[(wc * 64 + i2 * 16 + lr) * 32 + lk];
    }
#pragma unroll
    for (int i2 = 0; i2 < 4; ++i2)
#pragma unroll
      for (int j = 0; j < 4; ++j)
        acc[i2][j] = __builtin_amdgcn_mfma_f32_16x16x32_f16(af[i2], bfr[j], acc[i2][j], 0, 0, 0);
  }
  const int cr = (lane >> 4) * 4, cc = lane & 15;
#pragma unroll
  for (int i2 = 0; i2 < 4; ++i2) {
#pragma unroll
    for (int j = 0; j < 4; ++j) {
      const int m0 = mBase + wr * 64 + i2 * 16 + cr;
      const int n0 = nBase + wc * 64 + j * 16 + cc;
#pragma unroll
      for (int g2 = 0; g2 < 4; ++g2) {
        float v = acc[i2][j][g2] + bias[m0 + g2];
        if (MODE == 0) {
          const int m = m0 + g2;
          if (z == 2) {
            // V fragment-major: [bh][tile32][ks4][j2][ri2][lane64][8]
            const int ri = m >> 9, mm = m & 511;
            const int h = mm >> 6, dloc = mm & 63;
            const int jj = dloc >> 5, q31 = dloc & 31;
            const int b = n0 >> 11, s = n0 & 2047;
            const int tile = s >> 6, ks = (s >> 4) & 3, hi = (s >> 3) & 1, e = s & 7;
            const size_t flat =
                ((((((size_t)(b * 8 + h) * 32 + tile) * 4 + ks) * 2 + jj) * 2 + ri) * 64 +
                 hi * 32 + q31) * 8 + e;
            Cb[flat] = f2h(v);
          } else {
            Cb[(size_t)m * 8192 + n0] = f2h(v);
          }
        } else {
          const int m = m0 + g2;
          const int c = m >> 9, o = m & 511;
          const int b = n0 >> 11, s = n0 & 2047;
          Cf[(size_t)b * 2097152 + (size_t)o * 4096 + c * 2048 + s] = v;
        }
      }
    }
  }
}

// ---------------- magnitudes: Qm row-major [(bh*2048+s)][64]; Km FRAGMENT-major ----------------
// Km_f: [bh][tile32][kb2][db4][lane64][8] so attn's kf loads are lane-contiguous 1KB.
__global__ __launch_bounds__(256) void mag_qk(
    const unsigned short* __restrict__ Cq, const unsigned short* __restrict__ Ck,
    unsigned short* __restrict__ Qm, unsigned short* __restrict__ Km) {
  __shared__ unsigned short tl[64][72];
  const int isK = blockIdx.z;
  const unsigned short* C = isK ? Ck : Cq;
  unsigned short* Out = isK ? Km : Qm;
  const int t = threadIdx.x;
  const int sBase = blockIdx.x * 64;
  const int bh = blockIdx.y, b = bh >> 3, h = bh & 7;
  const int d = t >> 2, sc = (t & 3) * 16;
  const unsigned short* pr = C + (size_t)(h * 64 + d) * 8192 + b * 2048 + sBase + sc;
  const unsigned short* pi = pr + (size_t)512 * 8192;
  unsigned short rb[16], ib[16];
  *(uint4*)&rb[0] = *(const uint4*)pr;  *(uint4*)&rb[8] = *(const uint4*)(pr + 8);
  *(uint4*)&ib[0] = *(const uint4*)pi;  *(uint4*)&ib[8] = *(const uint4*)(pi + 8);
#pragma unroll
  for (int j = 0; j < 16; ++j) {
    float fr = h2f(rb[j]), fi = h2f(ib[j]);
    tl[sc + j][d] = f2h(sqrtf(fr * fr + fi * fi + 1e-8f));
  }
  __syncthreads();
  const int s = t >> 2, dc = (t & 3) * 16;
  if (isK) {
    const int kb = s >> 5, q31 = s & 31, db = dc >> 4;
    unsigned short* dstf = Out +
        ((((size_t)bh * 32 + blockIdx.x) * 2 + kb) * 4 + db) * 512 + (size_t)q31 * 8;
    *(uint4*)dstf = *(const uint4*)&tl[s][dc];               // hi = 0
    *(uint4*)(dstf + 256) = *(const uint4*)&tl[s][dc + 8];   // hi = 1
  } else {
    unsigned short* dst = Out + ((size_t)bh * 2048 + sBase + s) * 64 + dc;
    *(uint4*)dst = *(const uint4*)&tl[s][dc];
    *(uint4*)(dst + 8) = *(const uint4*)&tl[s][dc + 8];
  }
}

// ---------------- flash attention (R9 config): LDS-free swapped 32x32, fragment-major K/V ----------------
// 512 blocks, 1 full KV sweep per block. Per wave: 32 q-rows. QK^T swapped:
// mfma(A=K, B=Q) -> S col=lane&31=q, row(reg)=kv. Softmax lane-local;
// P -> PV A-frags via cvt_pkrtz + v_permlane32_swap_b32. All loads lane-contiguous 1KB.
__global__ __launch_bounds__(256) void attn(
    const unsigned short* __restrict__ Qm, const unsigned short* __restrict__ Km,
    const unsigned short* __restrict__ Vf, unsigned short* __restrict__ OutT) {
  const int t = threadIdx.x, wave = t >> 6, lane = t & 63;
  // XCD-aware decode: same-bh blocks share an XCD's L2 (id%8 = XCD round-robin)
  const int id = blockIdx.x;
  const int xcd = id & 7, within = id >> 3;
  const int bh = xcd * 4 + (within >> 4);
  const int qtile = within & 15;
  const int b = bh >> 3, h = bh & 7;
  const int q31 = lane & 31, hi = lane >> 5;
  const int qBase = qtile * 128 + wave * 32;
  const float ls = 0.18033688f;  // log2(e)/sqrt(DK)

  // Q B-frags (col=q, k=d): 4 frags over DK=64
  f16x8 qf[4];
  {
    const unsigned short* qp = Qm + ((size_t)bh * 2048 + qBase + q31) * 64 + hi * 8;
    qf[0] = *(const f16x8*)qp;
    qf[1] = *(const f16x8*)(qp + 16);
    qf[2] = *(const f16x8*)(qp + 32);
    qf[3] = *(const f16x8*)(qp + 48);
  }
  f32x16 Or[2] = {}, Oi[2] = {};
  float m = -1e30f, l = 0.f;

  // fragment-major bases (lane-contiguous)
  const unsigned short* kmF = Km + (size_t)bh * 131072 + (size_t)lane * 8;
  const unsigned short* vF  = Vf + (size_t)bh * 262144 + (size_t)lane * 8;

  for (int t0 = 0; t0 < 2048; t0 += 64) {
    const int tile = t0 >> 6;
    // ---- batch K loads (8 x 1KB coalesced) ----
    f16x8 kf[2][4];
#pragma unroll
    for (int kb = 0; kb < 2; ++kb)
#pragma unroll
      for (int db = 0; db < 4; ++db)
        kf[kb][db] = *(const f16x8*)(kmF + (size_t)(((tile * 2 + kb) * 4 + db)) * 512);
    __builtin_amdgcn_sched_barrier(0);
    // ---- QK^T (swapped): S[kb] = K x Q, col=q row=kv ----
    f32x16 S[2] = {};
#pragma unroll
    for (int kb = 0; kb < 2; ++kb)
#pragma unroll
      for (int db = 0; db < 4; ++db)
        S[kb] = __builtin_amdgcn_mfma_f32_32x32x16_f16(kf[kb][db], qf[db], S[kb], 0, 0, 0);
    // ---- batch V loads (16 x 1KB coalesced); latency hides under softmax ----
    f16x8 vr[4][2], vi[4][2];
#pragma unroll
    for (int ks = 0; ks < 4; ++ks)
#pragma unroll
      for (int j = 0; j < 2; ++j) {
        const size_t u = (size_t)(((tile * 4 + ks) * 2 + j) * 2) * 512;
        vr[ks][j] = *(const f16x8*)(vF + u);
        vi[ks][j] = *(const f16x8*)(vF + u + 512);
      }
    __builtin_amdgcn_sched_barrier(0);
    // ---- row max (lane-local + 1 cross-half shuffle) ----
    float m0a = fmaxf(S[0][0], S[0][1]), m0b = fmaxf(S[0][2], S[0][3]);
#pragma unroll
    for (int r = 4; r < 16; r += 4) {
      m0a = fmaxf(m0a, fmaxf(S[0][r], S[0][r + 1]));
      m0b = fmaxf(m0b, fmaxf(S[0][r + 2], S[0][r + 3]));
    }
#pragma unroll
    for (int r = 0; r < 16; r += 4) {
      m0a = fmaxf(m0a, fmaxf(S[1][r], S[1][r + 1]));
      m0b = fmaxf(m0b, fmaxf(S[1][r + 2], S[1][r + 3]));
    }
    float vmax = fmaxf(m0a, m0b);
    vmax = fmaxf(vmax, __shfl_xor(vmax, 32, 64));
    float pmax = vmax * ls;
    // ---- defer-max rescale (rare): al lives at lane=q, O rows are q=qloc -> shfl ----
    if (__any(pmax > m + 8.0f)) {
      float mnew = fmaxf(m, pmax);
      float al = __builtin_amdgcn_exp2f(m - mnew);
      m = mnew;
      l *= al;
#pragma unroll
      for (int r = 0; r < 16; ++r) {
        const int qloc = (r & 3) + 8 * (r >> 2) + 4 * hi;
        float ao = __shfl(al, qloc, 64);
        Or[0][r] *= ao; Or[1][r] *= ao;
        Oi[0][r] *= ao; Oi[1][r] *= ao;
      }
    }
    // ---- p = exp2(S*ls - m), lane-local sum ----
    float p[2][16];
    float ps0 = 0.f, ps1 = 0.f;
#pragma unroll
    for (int kb = 0; kb < 2; ++kb)
#pragma unroll
      for (int r = 0; r < 16; r += 2) {
        float pa_ = __builtin_amdgcn_exp2f(fmaf(S[kb][r], ls, -m));
        float pb_ = __builtin_amdgcn_exp2f(fmaf(S[kb][r + 1], ls, -m));
        p[kb][r] = pa_; p[kb][r + 1] = pb_;
        ps0 += pa_; ps1 += pb_;
      }
    float ps = ps0 + ps1;
    ps += __shfl_xor(ps, 32, 64);
    l += ps;
    // ---- P -> PV A-frags: cvt_pkrtz + permlane32_swap (exchange across lane halves) ----
    f16x8 pa[4];
#pragma unroll
    for (int ks = 0; ks < 4; ++ks) {
      const float* pp = &p[ks >> 1][8 * (ks & 1)];
      unsigned c0 = pkrtz(pp[0], pp[1]);
      unsigned c1 = pkrtz(pp[2], pp[3]);
      unsigned d0 = pkrtz(pp[4], pp[5]);
      unsigned d1 = pkrtz(pp[6], pp[7]);
      asm volatile("v_permlane32_swap_b32 %0, %1" : "+v"(c0), "+v"(d0));
      asm volatile("v_permlane32_swap_b32 %0, %1" : "+v"(c1), "+v"(d1));
      union { unsigned u[4]; f16x8 v; } w;
      w.u[0] = c0; w.u[1] = c1; w.u[2] = d0; w.u[3] = d1;
      pa[ks] = w.v;
    }
    // ---- PV: O[j] += P x V (B col=d, k=kv), V already in registers ----
#pragma unroll
    for (int ks = 0; ks < 4; ++ks)
#pragma unroll
      for (int j = 0; j < 2; ++j) {
        Or[j] = __builtin_amdgcn_mfma_f32_32x32x16_f16(pa[ks], vr[ks][j], Or[j], 0, 0, 0);
        Oi[j] = __builtin_amdgcn_mfma_f32_32x32x16_f16(pa[ks], vi[ks][j], Oi[j], 0, 0, 0);
      }
  }
  // ---- epilogue: divide by row-sum (redistribute to O layout), store ----
  float linv = 1.0f / l;
#pragma unroll
  for (int r = 0; r < 16; ++r) {
    const int qloc = (r & 3) + 8 * (r >> 2) + 4 * hi;
    float iv = __shfl(linv, qloc, 64);
    unsigned short* orow = OutT + ((size_t)b * 2048 + qBase + qloc) * 1024 + h * 64;
    orow[q31]       = f2h(Or[0][r] * iv);
    orow[32 + q31]  = f2h(Or[1][r] * iv);
    orow[512 + q31] = f2h(Oi[0][r] * iv);
    orow[544 + q31] = f2h(Oi[1][r] * iv);
  }
}

extern "C" void kernel_launch(void* const* d_in, const int* in_sizes, int n_in,
                              void* d_out, int out_size, void* d_ws, size_t ws_size,
                              hipStream_t stream) {
  (void)in_sizes; (void)n_in; (void)out_size; (void)ws_size;
  const float* x = (const float*)d_in[0];

  // workspace layout: XT 16.78M | W2 8.39M | bias2 16K | Cqkv 50.33M  => ~75.5 MB
  unsigned short* XT = (unsigned short*)d_ws;
  unsigned short* W2 = XT + (size_t)8192 * 1024;
  float* bias2 = (float*)(W2 + (size_t)4 * 1024 * 1024);
  unsigned short* Cqkv = (unsigned short*)(bias2 + 4096);
  // Qm/Km live in d_out (dead before final GEMM overwrites d_out)
  unsigned short* Qm = (unsigned short*)d_out;
  unsigned short* Km = Qm + (size_t)4 * 8 * 2048 * 64;   // Km_f fragment-major, same size
  // V_f lives in the z=2 slab of Cqkv; OutT reuses Cq slab (dead after mag_qk)
  unsigned short* Vf = Cqkv + (size_t)2 * 1024 * 8192;
  unsigned short* OutT = Cqkv;

  pack_w4<<<dim3(4096, 4), 256, 0, stream>>>(
      (const float*)d_in[1],  (const float*)d_in[2],  (const float*)d_in[3],  (const float*)d_in[4],
      (const float*)d_in[5],  (const float*)d_in[6],  (const float*)d_in[7],  (const float*)d_in[8],
      (const float*)d_in[9],  (const float*)d_in[10], (const float*)d_in[11], (const float*)d_in[12],
      (const float*)d_in[13], (const float*)d_in[14], (const float*)d_in[15], (const float*)d_in[16],
      W2, bias2);
  pack_x<<<dim3(32, 8, 8), 256, 0, stream>>>(x, XT);
  gemm_bt<0><<<1536, 256, 0, stream>>>(W2, XT, bias2, Cqkv, nullptr);
  mag_qk<<<dim3(32, 32, 2), 256, 0, stream>>>(Cqkv, Cqkv + (size_t)1024 * 8192, Qm, Km);
  attn<<<512, 256, 0, stream>>>(Qm, Km, Vf, OutT);
  gemm_bt<1><<<512, 256, 0, stream>>>(
      W2 + (size_t)3 * 1024 * 1024, OutT, bias2 + 3 * 1024, nullptr, (float*)d_out);
}

// Round 15
// 205.943 us; speedup vs baseline: 1.9302x; 1.0022x over previous
//
#include <hip/hip_runtime.h>
#include <math.h>
#include <stdint.h>

typedef __attribute__((ext_vector_type(8))) _Float16 f16x8;
typedef __attribute__((ext_vector_type(2))) __fp16 fp16x2;
typedef __attribute__((ext_vector_type(4))) float f32x4;
typedef __attribute__((ext_vector_type(16))) float f32x16;

static __device__ __forceinline__ unsigned short f2h(float f) {
  union { _Float16 h; unsigned short u; } v; v.h = (_Float16)f;
  return v.u;
}
static __device__ __forceinline__ float h2f(unsigned short u) {
  union { unsigned short u; _Float16 h; } v; v.u = u;
  return (float)v.h;
}
static __device__ __forceinline__ unsigned pkrtz(float a, float b) {
  union { fp16x2 h; unsigned u; } v;
  v.h = __builtin_amdgcn_cvt_pkrtz(a, b);
  return v.u;
}

#define GLOAD_LDS16(g, l) __builtin_amdgcn_global_load_lds( \
    (const __attribute__((address_space(1))) void*)(g),     \
    (__attribute__((address_space(3))) void*)(l), 16, 0, 0)

// ---------------- pack weights (all 4 sets in one dispatch): W2 = [[Wr,-Wi],[Wi,Wr]] ----------------
__global__ __launch_bounds__(256) void pack_w4(
    const float* __restrict__ Wr0, const float* __restrict__ Wi0,
    const float* __restrict__ br0, const float* __restrict__ bi0,
    const float* __restrict__ Wr1, const float* __restrict__ Wi1,
    const float* __restrict__ br1, const float* __restrict__ bi1,
    const float* __restrict__ Wr2, const float* __restrict__ Wi2,
    const float* __restrict__ br2, const float* __restrict__ bi2,
    const float* __restrict__ Wr3, const float* __restrict__ Wi3,
    const float* __restrict__ br3, const float* __restrict__ bi3,
    unsigned short* __restrict__ W2, float* __restrict__ bias2) {
  const int s = blockIdx.y;
  const float* Wr = (s == 0) ? Wr0 : (s == 1) ? Wr1 : (s == 2) ? Wr2 : Wr3;
  const float* Wi = (s == 0) ? Wi0 : (s == 1) ? Wi1 : (s == 2) ? Wi2 : Wi3;
  const float* br = (s == 0) ? br0 : (s == 1) ? br1 : (s == 2) ? br2 : br3;
  const float* bi = (s == 0) ? bi0 : (s == 1) ? bi1 : (s == 2) ? bi2 : bi3;
  W2 += (size_t)s * 1024 * 1024;
  bias2 += s * 1024;
  int idx = blockIdx.x * 256 + threadIdx.x;
  int m = idx >> 10, k = idx & 1023;
  int o = m & 511, d = k & 511;
  float v;
  if (m < 512) v = (k < 512) ? Wr[o * 512 + d] : -Wi[o * 512 + d];
  else         v = (k < 512) ? Wi[o * 512 + d] :  Wr[o * 512 + d];
  W2[idx] = f2h(v);
  if (idx < 1024) {
    int oo = idx & 511;
    bias2[idx] = (idx < 512) ? (br[oo] - bi[oo]) : (br[oo] + bi[oo]);
  }
}

// ---------------- pack x: (B,D,2,S) f32 -> XT[(b*2048+s)][(c*512+d)] f16 (B^T layout) ----------------
__global__ __launch_bounds__(256) void pack_x(
    const float* __restrict__ x, unsigned short* __restrict__ XT) {
  __shared__ unsigned short tl[64][72];
  const int t = threadIdx.x;
  const int sBase = blockIdx.x * 64, dBase = blockIdx.y * 64;
  const int b = blockIdx.z >> 1, c = blockIdx.z & 1;
  const int r = t >> 2, cb = (t & 3) * 16;
  const float* src = x + (((size_t)(b * 512 + dBase + r) * 2 + c) * 2048 + sBase + cb);
#pragma unroll
  for (int j = 0; j < 16; j += 4) {
    float4 v = *(const float4*)(src + j);
    tl[cb + j + 0][r] = f2h(v.x);
    tl[cb + j + 1][r] = f2h(v.y);
    tl[cb + j + 2][r] = f2h(v.z);
    tl[cb + j + 3][r] = f2h(v.w);
  }
  __syncthreads();
  const int s = t >> 2, dc = (t & 3) * 16;
  unsigned short* dst = XT + ((size_t)(b * 2048 + sBase + s)) * 1024 + c * 512 + dBase + dc;
  *(uint4*)dst = *(const uint4*)&tl[s][dc];
  *(uint4*)(dst + 8) = *(const uint4*)&tl[s][dc + 8];
}

// ---------------- GEMM: C[1024][8192] = A(1024x1024) * Bt(8192x1024)^T, f16 in, fp32 acc ----------------
// 1D grid, XCD-swizzled: xcd=bid&7 owns n-tiles [8*xcd, 8*xcd+8) -> A+B panels fit 4MB L2.
// MODE 0: z=0,1 (Q,K): f16 channel-major; z=2 (V): fragment-major V_f for attn.
// MODE 1: fp32 scattered into d_out (B,D,2,S).
template <int MODE>
__global__ __launch_bounds__(256) void gemm_bt(
    const unsigned short* __restrict__ A, const unsigned short* __restrict__ Bt,
    const float* __restrict__ bias, unsigned short* __restrict__ Cb,
    float* __restrict__ Cf) {
  __shared__ unsigned short As[128 * 32];
  __shared__ unsigned short Bs[128 * 32];
  const int t = threadIdx.x;
  const int wave = t >> 6, lane = t & 63;
  const int wr = wave >> 1, wc = wave & 1;
  const int bid = blockIdx.x;
  const int xcd = bid & 7, g = bid >> 3;
  const int i = g & 63, z = g >> 6;
  const int nb = xcd * 8 + (i >> 3), mb = i & 7;
  const int mBase = mb * 128, nBase = nb * 128;
  A += (size_t)z * 1024 * 1024;
  bias += z * 1024;
  if (MODE == 0) Cb += (size_t)z * 1024 * 8192;
  const int lr = lane & 15, lk = (lane >> 4) * 8;
  f32x4 acc[4][4] = {};
  const int grow = wave * 32 + (lane >> 2);
  const int gcol = (lane & 3) * 8;
  const unsigned short* ga = A + (size_t)(mBase + grow) * 1024 + gcol;
  const unsigned short* gb = Bt + (size_t)(nBase + grow) * 1024 + gcol;
  unsigned short* lA = &As[wave * 1024];
  unsigned short* lB = &Bs[wave * 1024];
  for (int k0 = 0; k0 < 1024; k0 += 32) {
    __syncthreads();
    GLOAD_LDS16(ga + k0, lA);
    GLOAD_LDS16(ga + 16 * 1024 + k0, lA + 512);
    GLOAD_LDS16(gb + k0, lB);
    GLOAD_LDS16(gb + 16 * 1024 + k0, lB + 512);
    __syncthreads();
    f16x8 af[4], bfr[4];
#pragma unroll
    for (int i2 = 0; i2 < 4; ++i2) {
      af[i2]  = *(const f16x8*)&As[(wr * 64 + i2 * 16 + lr) * 32 + lk];
      bfr[i2] = *(const f16x8*)&Bs[(wc * 64 + i2 * 16 + lr) * 32 + lk];
    }
#pragma unroll
    for (int i2 = 0; i2 < 4; ++i2)
#pragma unroll
      for (int j = 0; j < 4; ++j)
        acc[i2][j] = __builtin_amdgcn_mfma_f32_16x16x32_f16(af[i2], bfr[j], acc[i2][j], 0, 0, 0);
  }
  const int cr = (lane >> 4) * 4, cc = lane & 15;
#pragma unroll
  for (int i2 = 0; i2 < 4; ++i2) {
#pragma unroll
    for (int j = 0; j < 4; ++j) {
      const int m0 = mBase + wr * 64 + i2 * 16 + cr;
      const int n0 = nBase + wc * 64 + j * 16 + cc;
#pragma unroll
      for (int g2 = 0; g2 < 4; ++g2) {
        float v = acc[i2][j][g2] + bias[m0 + g2];
        if (MODE == 0) {
          const int m = m0 + g2;
          if (z == 2) {
            // V fragment-major: [bh][tile32][ks4][j2][ri2][lane64][8]
            const int ri = m >> 9, mm = m & 511;
            const int h = mm >> 6, dloc = mm & 63;
            const int jj = dloc >> 5, q31 = dloc & 31;
            const int b = n0 >> 11, s = n0 & 2047;
            const int tile = s >> 6, ks = (s >> 4) & 3, hi = (s >> 3) & 1, e = s & 7;
            const size_t flat =
                ((((((size_t)(b * 8 + h) * 32 + tile) * 4 + ks) * 2 + jj) * 2 + ri) * 64 +
                 hi * 32 + q31) * 8 + e;
            Cb[flat] = f2h(v);
          } else {
            Cb[(size_t)m * 8192 + n0] = f2h(v);
          }
        } else {
          const int m = m0 + g2;
          const int c = m >> 9, o = m & 511;
          const int b = n0 >> 11, s = n0 & 2047;
          Cf[(size_t)b * 2097152 + (size_t)o * 4096 + c * 2048 + s] = v;
        }
      }
    }
  }
}

// ---------------- magnitudes: Qm row-major [(bh*2048+s)][64]; Km FRAGMENT-major ----------------
// Km_f: [bh][tile32][kb2][db4][lane64][8] so attn's kf loads are lane-contiguous 1KB.
__global__ __launch_bounds__(256) void mag_qk(
    const unsigned short* __restrict__ Cq, const unsigned short* __restrict__ Ck,
    unsigned short* __restrict__ Qm, unsigned short* __restrict__ Km) {
  __shared__ unsigned short tl[64][72];
  const int isK = blockIdx.z;
  const unsigned short* C = isK ? Ck : Cq;
  unsigned short* Out = isK ? Km : Qm;
  const int t = threadIdx.x;
  const int sBase = blockIdx.x * 64;
  const int bh = blockIdx.y, b = bh >> 3, h = bh & 7;
  const int d = t >> 2, sc = (t & 3) * 16;
  const unsigned short* pr = C + (size_t)(h * 64 + d) * 8192 + b * 2048 + sBase + sc;
  const unsigned short* pi = pr + (size_t)512 * 8192;
  unsigned short rb[16], ib[16];
  *(uint4*)&rb[0] = *(const uint4*)pr;  *(uint4*)&rb[8] = *(const uint4*)(pr + 8);
  *(uint4*)&ib[0] = *(const uint4*)pi;  *(uint4*)&ib[8] = *(const uint4*)(pi + 8);
#pragma unroll
  for (int j = 0; j < 16; ++j) {
    float fr = h2f(rb[j]), fi = h2f(ib[j]);
    tl[sc + j][d] = f2h(sqrtf(fr * fr + fi * fi + 1e-8f));
  }
  __syncthreads();
  const int s = t >> 2, dc = (t & 3) * 16;
  if (isK) {
    const int kb = s >> 5, q31 = s & 31, db = dc >> 4;
    unsigned short* dstf = Out +
        ((((size_t)bh * 32 + blockIdx.x) * 2 + kb) * 4 + db) * 512 + (size_t)q31 * 8;
    *(uint4*)dstf = *(const uint4*)&tl[s][dc];               // hi = 0
    *(uint4*)(dstf + 256) = *(const uint4*)&tl[s][dc + 8];   // hi = 1
  } else {
    unsigned short* dst = Out + ((size_t)bh * 2048 + sBase + s) * 64 + dc;
    *(uint4*)dst = *(const uint4*)&tl[s][dc];
    *(uint4*)(dst + 8) = *(const uint4*)&tl[s][dc + 8];
  }
}

// ---------------- flash attention: swapped 32x32, fragment-major K/V + loop-carried K prefetch ----------------
// 512 blocks (2/CU -> 2 waves/SIMD -> VGPR budget 256; we use ~150).
// kfA/kfB ping-pong: K(t+1) issues BEFORE QK(t) consumes kfA -> K latency fully hidden.
__global__ __launch_bounds__(256) void attn(
    const unsigned short* __restrict__ Qm, const unsigned short* __restrict__ Km,
    const unsigned short* __restrict__ Vf, unsigned short* __restrict__ OutT) {
  const int t = threadIdx.x, wave = t >> 6, lane = t & 63;
  const int id = blockIdx.x;
  const int xcd = id & 7, within = id >> 3;
  const int bh = xcd * 4 + (within >> 4);
  const int qtile = within & 15;
  const int b = bh >> 3, h = bh & 7;
  const int q31 = lane & 31, hi = lane >> 5;
  const int qBase = qtile * 128 + wave * 32;
  const float ls = 0.18033688f;  // log2(e)/sqrt(DK)

  f16x8 qf[4];
  {
    const unsigned short* qp = Qm + ((size_t)bh * 2048 + qBase + q31) * 64 + hi * 8;
    qf[0] = *(const f16x8*)qp;
    qf[1] = *(const f16x8*)(qp + 16);
    qf[2] = *(const f16x8*)(qp + 32);
    qf[3] = *(const f16x8*)(qp + 48);
  }
  f32x16 Or[2] = {}, Oi[2] = {};
  float m = -1e30f, l = 0.f;

  const unsigned short* kmF = Km + (size_t)bh * 131072 + (size_t)lane * 8;
  const unsigned short* vF  = Vf + (size_t)bh * 262144 + (size_t)lane * 8;

  // K prefetch helper: 8 x 1KB coalesced loads for one tile
  auto loadK = [&](f16x8 (&KF)[2][4], int tl_) {
#pragma unroll
    for (int kb = 0; kb < 2; ++kb)
#pragma unroll
      for (int db = 0; db < 4; ++db)
        KF[kb][db] = *(const f16x8*)(kmF + (size_t)((tl_ * 2 + kb) * 4 + db) * 512);
  };

  // one KV-tile body: QK(kf) -> V loads -> softmax -> PV
  auto body = [&](int tile, f16x8 (&KF)[2][4]) {
    f32x16 S[2] = {};
#pragma unroll
    for (int kb = 0; kb < 2; ++kb)
#pragma unroll
      for (int db = 0; db < 4; ++db)
        S[kb] = __builtin_amdgcn_mfma_f32_32x32x16_f16(KF[kb][db], qf[db], S[kb], 0, 0, 0);
    // V loads (16 x 1KB coalesced); latency hides under softmax
    f16x8 vr[4][2], vi[4][2];
#pragma unroll
    for (int ks = 0; ks < 4; ++ks)
#pragma unroll
      for (int j = 0; j < 2; ++j) {
        const size_t u = (size_t)(((tile * 4 + ks) * 2 + j) * 2) * 512;
        vr[ks][j] = *(const f16x8*)(vF + u);
        vi[ks][j] = *(const f16x8*)(vF + u + 512);
      }
    __builtin_amdgcn_sched_barrier(0);
    // row max (lane-local + 1 cross-half shuffle)
    float m0a = fmaxf(S[0][0], S[0][1]), m0b = fmaxf(S[0][2], S[0][3]);
#pragma unroll
    for (int r = 4; r < 16; r += 4) {
      m0a = fmaxf(m0a, fmaxf(S[0][r], S[0][r + 1]));
      m0b = fmaxf(m0b, fmaxf(S[0][r + 2], S[0][r + 3]));
    }
#pragma unroll
    for (int r = 0; r < 16; r += 4) {
      m0a = fmaxf(m0a, fmaxf(S[1][r], S[1][r + 1]));
      m0b = fmaxf(m0b, fmaxf(S[1][r + 2], S[1][r + 3]));
    }
    float vmax = fmaxf(m0a, m0b);
    vmax = fmaxf(vmax, __shfl_xor(vmax, 32, 64));
    float pmax = vmax * ls;
    // defer-max rescale (rare): al lives at lane=q, O rows are q=qloc -> shfl
    if (__any(pmax > m + 8.0f)) {
      float mnew = fmaxf(m, pmax);
      float al = __builtin_amdgcn_exp2f(m - mnew);
      m = mnew;
      l *= al;
#pragma unroll
      for (int r = 0; r < 16; ++r) {
        const int qloc = (r & 3) + 8 * (r >> 2) + 4 * hi;
        float ao = __shfl(al, qloc, 64);
        Or[0][r] *= ao; Or[1][r] *= ao;
        Oi[0][r] *= ao; Oi[1][r] *= ao;
      }
    }
    // p = exp2(S*ls - m), lane-local sum
    float p[2][16];
    float ps0 = 0.f, ps1 = 0.f;
#pragma unroll
    for (int kb = 0; kb < 2; ++kb)
#pragma unroll
      for (int r = 0; r < 16; r += 2) {
        float pa_ = __builtin_amdgcn_exp2f(fmaf(S[kb][r], ls, -m));
        float pb_ = __builtin_amdgcn_exp2f(fmaf(S[kb][r + 1], ls, -m));
        p[kb][r] = pa_; p[kb][r + 1] = pb_;
        ps0 += pa_; ps1 += pb_;
      }
    float ps = ps0 + ps1;
    ps += __shfl_xor(ps, 32, 64);
    l += ps;
    // P -> PV A-frags: cvt_pkrtz + permlane32_swap
    f16x8 pa[4];
#pragma unroll
    for (int ks = 0; ks < 4; ++ks) {
      const float* pp = &p[ks >> 1][8 * (ks & 1)];
      unsigned c0 = pkrtz(pp[0], pp[1]);
      unsigned c1 = pkrtz(pp[2], pp[3]);
      unsigned d0 = pkrtz(pp[4], pp[5]);
      unsigned d1 = pkrtz(pp[6], pp[7]);
      asm volatile("v_permlane32_swap_b32 %0, %1" : "+v"(c0), "+v"(d0));
      asm volatile("v_permlane32_swap_b32 %0, %1" : "+v"(c1), "+v"(d1));
      union { unsigned u[4]; f16x8 v; } w;
      w.u[0] = c0; w.u[1] = c1; w.u[2] = d0; w.u[3] = d1;
      pa[ks] = w.v;
    }
    // PV: O[j] += P x V
#pragma unroll
    for (int ks = 0; ks < 4; ++ks)
#pragma unroll
      for (int j = 0; j < 2; ++j) {
        Or[j] = __builtin_amdgcn_mfma_f32_32x32x16_f16(pa[ks], vr[ks][j], Or[j], 0, 0, 0);
        Oi[j] = __builtin_amdgcn_mfma_f32_32x32x16_f16(pa[ks], vi[ks][j], Oi[j], 0, 0, 0);
      }
  };

  f16x8 kfA[2][4], kfB[2][4];
  loadK(kfA, 0);  // prologue
  for (int tile = 0; tile < 32; tile += 2) {
    // sub-iter A: prefetch K(tile+1) into kfB, then consume kfA
    loadK(kfB, tile + 1);
    __builtin_amdgcn_sched_barrier(0);
    body(tile, kfA);
    // sub-iter B: prefetch K((tile+2)&31) into kfA (wrap keeps addr in-bounds; unused at end)
    loadK(kfA, (tile + 2) & 31);
    __builtin_amdgcn_sched_barrier(0);
    body(tile + 1, kfB);
  }
  // epilogue: divide by row-sum (redistribute to O layout), store
  float linv = 1.0f / l;
#pragma unroll
  for (int r = 0; r < 16; ++r) {
    const int qloc = (r & 3) + 8 * (r >> 2) + 4 * hi;
    float iv = __shfl(linv, qloc, 64);
    unsigned short* orow = OutT + ((size_t)b * 2048 + qBase + qloc) * 1024 + h * 64;
    orow[q31]       = f2h(Or[0][r] * iv);
    orow[32 + q31]  = f2h(Or[1][r] * iv);
    orow[512 + q31] = f2h(Oi[0][r] * iv);
    orow[544 + q31] = f2h(Oi[1][r] * iv);
  }
}

extern "C" void kernel_launch(void* const* d_in, const int* in_sizes, int n_in,
                              void* d_out, int out_size, void* d_ws, size_t ws_size,
                              hipStream_t stream) {
  (void)in_sizes; (void)n_in; (void)out_size; (void)ws_size;
  const float* x = (const float*)d_in[0];

  // workspace layout: XT 16.78M | W2 8.39M | bias2 16K | Cqkv 50.33M  => ~75.5 MB
  unsigned short* XT = (unsigned short*)d_ws;
  unsigned short* W2 = XT + (size_t)8192 * 1024;
  float* bias2 = (float*)(W2 + (size_t)4 * 1024 * 1024);
  unsigned short* Cqkv = (unsigned short*)(bias2 + 4096);
  // Qm/Km live in d_out (dead before final GEMM overwrites d_out)
  unsigned short* Qm = (unsigned short*)d_out;
  unsigned short* Km = Qm + (size_t)4 * 8 * 2048 * 64;   // Km_f fragment-major, same size
  // V_f lives in the z=2 slab of Cqkv; OutT reuses Cq slab (dead after mag_qk)
  unsigned short* Vf = Cqkv + (size_t)2 * 1024 * 8192;
  unsigned short* OutT = Cqkv;

  pack_w4<<<dim3(4096, 4), 256, 0, stream>>>(
      (const float*)d_in[1],  (const float*)d_in[2],  (const float*)d_in[3],  (const float*)d_in[4],
      (const float*)d_in[5],  (const float*)d_in[6],  (const float*)d_in[7],  (const float*)d_in[8],
      (const float*)d_in[9],  (const float*)d_in[10], (const float*)d_in[11], (const float*)d_in[12],
      (const float*)d_in[13], (const float*)d_in[14], (const float*)d_in[15], (const float*)d_in[16],
      W2, bias2);
  pack_x<<<dim3(32, 8, 8), 256, 0, stream>>>(x, XT);
  gemm_bt<0><<<1536, 256, 0, stream>>>(W2, XT, bias2, Cqkv, nullptr);
  mag_qk<<<dim3(32, 32, 2), 256, 0, stream>>>(Cqkv, Cqkv + (size_t)1024 * 8192, Qm, Km);
  attn<<<512, 256, 0, stream>>>(Qm, Km, Vf, OutT);
  gemm_bt<1><<<512, 256, 0, stream>>>(
      W2 + (size_t)3 * 1024 * 1024, OutT, bias2 + 3 * 1024, nullptr, (float*)d_out);
}